// Round 2
// baseline (911.707 us; speedup 1.0000x reference)
//
#include <hip/hip_runtime.h>
#include <hip/hip_bf16.h>
#include <stdint.h>

// Spatial local attention, MI355X bf16-MFMA implementation (conservative round:
// no global_load_lds, no tr-reads, no inline asm — verified fragment patterns only).
// Stages: prep_w -> qkv_conv(q,k,Vt) -> qk_gemm -> softmax_rows -> pv_gemm -> out_conv
//
// Workspace layout (bytes), total = 335,806,464 (~320.3 MiB):
//   [0       , 110592   ) Wqkv_t bf16 [9][192][32]
//   [110592  , 184320   ) Wo_t   bf16 [9][64][64]
//   [262144  , 67371008 ) q  bf16 [64][1024][512]   (reused as y_img bf16 [8][64][256][256])
//   [67371008, 134479872) k  bf16 [64][1024][512]
//   [134479872,201588736) Vt bf16 [64][512][1024]   (V transposed: [d][k])
//   [201588736,335806464) S/P bf16 [64][1024][1024]

using bf16 = __hip_bfloat16;
typedef short bf16x8 __attribute__((ext_vector_type(8)));
typedef float f32x4 __attribute__((ext_vector_type(4)));

__device__ __forceinline__ float b2f(unsigned short u) {
  union { unsigned int i; float f; } x; x.i = ((unsigned)u) << 16; return x.f;
}
__device__ __forceinline__ unsigned short f2b(float f) {
  __hip_bfloat16 h = __float2bfloat16(f);
  return *reinterpret_cast<unsigned short*>(&h);
}

// ---------------- weight prep: f32 OIHW -> bf16 [step][co][ci] ----------------
__global__ __launch_bounds__(256) void prep_w(const float* __restrict__ Wq, const float* __restrict__ Wk,
                                              const float* __restrict__ Wv, const float* __restrict__ Wo,
                                              bf16* __restrict__ wt, bf16* __restrict__ wot) {
  int i = blockIdx.x * 256 + threadIdx.x;
  if (i < 9 * 192 * 32) {              // wt[s][co192][ci]
    int ci = i & 31, co192 = (i >> 5) % 192, s = i / 6144;
    int dy = s / 3, dx = s % 3;
    int proj = co192 >> 6, co = co192 & 63;
    const float* Ws = (proj == 0) ? Wq : ((proj == 1) ? Wk : Wv);
    wt[i] = __float2bfloat16(Ws[((co * 32 + ci) * 3 + dy) * 3 + dx]);
  }
  if (i < 9 * 64 * 64) {               // wot[s][co][ci]
    int ci = i & 63, co = (i >> 6) & 63, s = i >> 12;
    wot[i] = __float2bfloat16(Wo[((co * 64 + ci) * 3 + (s / 3)) * 3 + (s % 3)]);
  }
}

// ---------------- QKV windowed conv (per-window zero pad) ----------------
// block: 2 windows (128 px), M=192 (q|k|v x 64co), K = 9 steps x 32ci. 4 waves split M.
__global__ __launch_bounds__(256) void qkv_conv(const float* __restrict__ x, const bf16* __restrict__ wt,
                                                const float* __restrict__ bq, const float* __restrict__ bk,
                                                const float* __restrict__ bv,
                                                bf16* __restrict__ qout, bf16* __restrict__ kout,
                                                bf16* __restrict__ vtout) {
  __shared__ bf16 xp[2 * 100 * 40];    // [win][py*10+px][ci pad40]
  int tid = threadIdx.x, bid = blockIdx.x;
  int t = bid >> 9, g = bid & 511;
  int gy = g >> 4, gx0 = (g & 15) * 2;

  unsigned int* xp32 = (unsigned int*)xp;
  for (int i = tid; i < 4000; i += 256) xp32[i] = 0u;
  __syncthreads();
  const float* xb = x + (size_t)t * 32 * 65536;
  #pragma unroll
  for (int it = 0; it < 16; ++it) {
    int e = tid + it * 256;
    int ix = e & 7, win = (e >> 3) & 1, iy = (e >> 4) & 7, ci = e >> 7;
    float val = xb[(size_t)ci * 65536 + (gy * 8 + iy) * 256 + (gx0 + win) * 8 + ix];
    xp[(win * 100 + (iy + 1) * 10 + (ix + 1)) * 40 + ci] = __float2bfloat16(val);
  }
  __syncthreads();

  int wv = tid >> 6, l = tid & 63, l15 = l & 15, lg = l >> 4;
  f32x4 z4 = {0.f, 0.f, 0.f, 0.f};
  f32x4 acc[3][8];
  for (int i = 0; i < 3; ++i) for (int j = 0; j < 8; ++j) acc[i][j] = z4;

  #pragma unroll
  for (int s = 0; s < 9; ++s) {
    const int dy = s / 3, dx = s % 3;
    bf16x8 a[3];
    #pragma unroll
    for (int mt = 0; mt < 3; ++mt)
      a[mt] = *(const bf16x8*)&wt[((size_t)s * 192 + wv * 48 + mt * 16 + l15) * 32 + lg * 8];
    #pragma unroll
    for (int nt = 0; nt < 8; ++nt) {
      int n = nt * 16 + l15;
      int win = n >> 6, px = n & 63;
      int iy = px >> 3, ix = px & 7;
      bf16x8 b = *(const bf16x8*)&xp[(win * 100 + (iy + dy) * 10 + (ix + dx)) * 40 + lg * 8];
      #pragma unroll
      for (int mt = 0; mt < 3; ++mt)
        acc[mt][nt] = __builtin_amdgcn_mfma_f32_16x16x32_bf16(a[mt], b, acc[mt][nt], 0, 0, 0);
    }
  }

  // epilogue: q/k at [t*8+head][win][jj*64+px]; V transposed at [t*8+head][jj*64+px][win]
  #pragma unroll
  for (int mt = 0; mt < 3; ++mt) {
    int c0 = wv * 48 + mt * 16 + lg * 4;
    int proj = c0 >> 6;
    const float* bptr = (proj == 0) ? bq : ((proj == 1) ? bk : bv);
    float bias[4];
    #pragma unroll
    for (int r = 0; r < 4; ++r) bias[r] = bptr[(c0 + r) & 63];
    #pragma unroll
    for (int nt = 0; nt < 8; ++nt) {
      int n = nt * 16 + l15;
      int win4 = n >> 6, px = n & 63;
      size_t gwin = (size_t)gy * 32 + gx0 + win4;
      #pragma unroll
      for (int r = 0; r < 4; ++r) {
        int co = (c0 + r) & 63;
        int head = co >> 3, jj = co & 7;
        size_t bh = (size_t)(t * 8 + head);
        bf16 val = __float2bfloat16(acc[mt][nt][r] + bias[r]);
        if (proj == 0)      qout[(bh * 1024 + gwin) * 512 + jj * 64 + px] = val;
        else if (proj == 1) kout[(bh * 1024 + gwin) * 512 + jj * 64 + px] = val;
        else                vtout[(bh * 512 + jj * 64 + px) * 1024 + gwin] = val;
      }
    }
  }
}

// ---------------- batched QK^T -> S bf16 (scaled), reg-staged LDS ----------------
__global__ __launch_bounds__(256) void qk_gemm(const bf16* __restrict__ q, const bf16* __restrict__ k,
                                               bf16* __restrict__ S) {
  __shared__ bf16 Atile[128 * 32];
  __shared__ bf16 Btile[128 * 32];
  int tid = threadIdx.x, bid = blockIdx.x;
  int batch = bid >> 6, tm = (bid >> 3) & 7, tn = bid & 7;
  const bf16* Qb = q + (size_t)batch * 1024 * 512 + (size_t)tm * 128 * 512;
  const bf16* Kb = k + (size_t)batch * 1024 * 512 + (size_t)tn * 128 * 512;
  int wv = tid >> 6, l = tid & 63, l15 = l & 15, lg = l >> 4;
  int wm = wv & 1, wn = wv >> 1;
  int srow = tid >> 2, koff = (tid & 3) * 8;
  f32x4 z4 = {0.f, 0.f, 0.f, 0.f};
  f32x4 acc[4][4];
  for (int i = 0; i < 4; ++i) for (int j = 0; j < 4; ++j) acc[i][j] = z4;

  for (int s = 0; s < 16; ++s) {
    bf16x8 a0 = *(const bf16x8*)&Qb[(size_t)srow * 512 + s * 32 + koff];
    bf16x8 a1 = *(const bf16x8*)&Qb[(size_t)(srow + 64) * 512 + s * 32 + koff];
    bf16x8 b0 = *(const bf16x8*)&Kb[(size_t)srow * 512 + s * 32 + koff];
    bf16x8 b1 = *(const bf16x8*)&Kb[(size_t)(srow + 64) * 512 + s * 32 + koff];
    __syncthreads();
    *(bf16x8*)&Atile[srow * 32 + koff] = a0;
    *(bf16x8*)&Atile[(srow + 64) * 32 + koff] = a1;
    *(bf16x8*)&Btile[srow * 32 + koff] = b0;
    *(bf16x8*)&Btile[(srow + 64) * 32 + koff] = b1;
    __syncthreads();
    bf16x8 a[4], b[4];
    #pragma unroll
    for (int i = 0; i < 4; ++i) {
      a[i] = *(const bf16x8*)&Atile[(wm * 64 + i * 16 + l15) * 32 + lg * 8];
      b[i] = *(const bf16x8*)&Btile[(wn * 64 + i * 16 + l15) * 32 + lg * 8];
    }
    #pragma unroll
    for (int i = 0; i < 4; ++i)
      #pragma unroll
      for (int j = 0; j < 4; ++j)
        acc[i][j] = __builtin_amdgcn_mfma_f32_16x16x32_bf16(a[i], b[j], acc[i][j], 0, 0, 0);
  }

  const float SCALE = 0.04419417382415922f;  // 1/sqrt(512)
  bf16* Sb = S + (size_t)batch * 1024 * 1024;
  #pragma unroll
  for (int i = 0; i < 4; ++i)
    #pragma unroll
    for (int j = 0; j < 4; ++j)
      #pragma unroll
      for (int r = 0; r < 4; ++r) {
        int row = tm * 128 + wm * 64 + i * 16 + lg * 4 + r;
        int col = tn * 128 + wn * 64 + j * 16 + l15;
        Sb[(size_t)row * 1024 + col] = __float2bfloat16(acc[i][j][r] * SCALE);
      }
}

// ---------------- row softmax (in place, 1 wave per 1024-row) ----------------
__global__ __launch_bounds__(256) void softmax_rows(bf16* __restrict__ S) {
  int l = threadIdx.x & 63;
  size_t row = (size_t)blockIdx.x * 4 + (threadIdx.x >> 6);
  bf16* p = S + row * 1024 + l * 16;
  bf16x8 s0 = *(const bf16x8*)p;
  bf16x8 s1 = *(const bf16x8*)(p + 8);
  float f[16];
  #pragma unroll
  for (int i = 0; i < 8; ++i) { f[i] = b2f((unsigned short)s0[i]); f[8 + i] = b2f((unsigned short)s1[i]); }
  float m = f[0];
  #pragma unroll
  for (int i = 1; i < 16; ++i) m = fmaxf(m, f[i]);
  for (int d = 1; d < 64; d <<= 1) m = fmaxf(m, __shfl_xor(m, d));
  float sum = 0.f;
  #pragma unroll
  for (int i = 0; i < 16; ++i) { f[i] = __expf(f[i] - m); sum += f[i]; }
  for (int d = 1; d < 64; d <<= 1) sum += __shfl_xor(sum, d);
  float r = 1.0f / sum;
  bf16x8 o0, o1;
  #pragma unroll
  for (int i = 0; i < 8; ++i) { o0[i] = (short)f2b(f[i] * r); o1[i] = (short)f2b(f[8 + i] * r); }
  *(bf16x8*)p = o0;
  *(bf16x8*)(p + 8) = o1;
}

// ---------------- batched PV (B = Vt rows) -> y image layout bf16 ----------------
__global__ __launch_bounds__(256) void pv_gemm(const bf16* __restrict__ P, const bf16* __restrict__ vt,
                                               bf16* __restrict__ y) {
  __shared__ bf16 Atile[128 * 32];
  __shared__ bf16 Btile[128 * 32];
  int tid = threadIdx.x, bid = blockIdx.x;
  int batch = bid >> 5, bq = (bid >> 2) & 7, bd = bid & 3;
  const bf16* Pb = P + (size_t)batch * 1024 * 1024 + (size_t)bq * 128 * 1024;
  const bf16* Vb = vt + (size_t)batch * 512 * 1024 + (size_t)bd * 128 * 1024;
  int wv = tid >> 6, l = tid & 63, l15 = l & 15, lg = l >> 4;
  int wm = wv & 1, wn = wv >> 1;
  int srow = tid >> 2, koff = (tid & 3) * 8;
  f32x4 z4 = {0.f, 0.f, 0.f, 0.f};
  f32x4 acc[4][4];
  for (int i = 0; i < 4; ++i) for (int j = 0; j < 4; ++j) acc[i][j] = z4;

  for (int s = 0; s < 32; ++s) {
    bf16x8 a0 = *(const bf16x8*)&Pb[(size_t)srow * 1024 + s * 32 + koff];
    bf16x8 a1 = *(const bf16x8*)&Pb[(size_t)(srow + 64) * 1024 + s * 32 + koff];
    bf16x8 b0 = *(const bf16x8*)&Vb[(size_t)srow * 1024 + s * 32 + koff];
    bf16x8 b1 = *(const bf16x8*)&Vb[(size_t)(srow + 64) * 1024 + s * 32 + koff];
    __syncthreads();
    *(bf16x8*)&Atile[srow * 32 + koff] = a0;
    *(bf16x8*)&Atile[(srow + 64) * 32 + koff] = a1;
    *(bf16x8*)&Btile[srow * 32 + koff] = b0;
    *(bf16x8*)&Btile[(srow + 64) * 32 + koff] = b1;
    __syncthreads();
    bf16x8 a[4], b[4];
    #pragma unroll
    for (int i = 0; i < 4; ++i) {
      a[i] = *(const bf16x8*)&Atile[(wm * 64 + i * 16 + l15) * 32 + lg * 8];
      b[i] = *(const bf16x8*)&Btile[(wn * 64 + i * 16 + l15) * 32 + lg * 8];
    }
    #pragma unroll
    for (int i = 0; i < 4; ++i)
      #pragma unroll
      for (int j = 0; j < 4; ++j)
        acc[i][j] = __builtin_amdgcn_mfma_f32_16x16x32_bf16(a[i], b[j], acc[i][j], 0, 0, 0);
  }

  int t = batch >> 3, h = batch & 7;
  #pragma unroll
  for (int i = 0; i < 4; ++i)
    #pragma unroll
    for (int j = 0; j < 4; ++j)
      #pragma unroll
      for (int r = 0; r < 4; ++r) {
        int win = bq * 128 + wm * 64 + i * 16 + lg * 4 + r;
        int d = bd * 128 + wn * 64 + j * 16 + l15;
        int jj = d >> 6, px = d & 63;
        int gy = win >> 5, gx = win & 31;
        y[((size_t)(t * 64 + h * 8 + jj) * 256 + gy * 8 + (px >> 3)) * 256 + gx * 8 + (px & 7)] =
            __float2bfloat16(acc[i][j][r]);
      }
}

// ---------------- final full-image conv + residual -> f32 out ----------------
__global__ __launch_bounds__(256) void out_conv(const bf16* __restrict__ yimg, const bf16* __restrict__ wot,
                                                const float* __restrict__ bo, float* __restrict__ out) {
  __shared__ bf16 yp[324 * 72];        // [py*18+px][ci pad72]
  int tid = threadIdx.x, bid = blockIdx.x;
  int t = bid >> 8, tile = bid & 255;
  int y0 = (tile >> 4) * 16, x0 = (tile & 15) * 16;
  const bf16* yb = yimg + (size_t)t * 64 * 65536;

  for (int e = tid; e < 18 * 18 * 64; e += 256) {
    int ppx = e % 18; int rem = e / 18; int ppy = rem % 18; int ci = rem / 18;
    int gy = y0 + ppy - 1, gx = x0 + ppx - 1;
    unsigned short val = 0;
    if ((unsigned)gy < 256u && (unsigned)gx < 256u)
      val = *(const unsigned short*)&yb[(size_t)ci * 65536 + gy * 256 + gx];
    *(unsigned short*)&yp[(ppy * 18 + ppx) * 72 + ci] = val;
  }
  __syncthreads();

  int wv = tid >> 6, l = tid & 63, l15 = l & 15, lg = l >> 4;
  int wm = wv & 1, wn = wv >> 1;
  f32x4 z4 = {0.f, 0.f, 0.f, 0.f};
  f32x4 acc[2][8];
  for (int i = 0; i < 2; ++i) for (int j = 0; j < 8; ++j) acc[i][j] = z4;

  #pragma unroll
  for (int s9 = 0; s9 < 9; ++s9) {
    const int dy = s9 / 3, dx = s9 % 3;
    #pragma unroll
    for (int half = 0; half < 2; ++half) {
      bf16x8 a[2];
      #pragma unroll
      for (int mt = 0; mt < 2; ++mt)
        a[mt] = *(const bf16x8*)&wot[((size_t)s9 * 64 + wm * 32 + mt * 16 + l15) * 64 + half * 32 + lg * 8];
      #pragma unroll
      for (int nt = 0; nt < 8; ++nt) {
        int ty = wn * 8 + nt;
        bf16x8 b = *(const bf16x8*)&yp[((ty + dy) * 18 + l15 + dx) * 72 + half * 32 + lg * 8];
        #pragma unroll
        for (int mt = 0; mt < 2; ++mt)
          acc[mt][nt] = __builtin_amdgcn_mfma_f32_16x16x32_bf16(a[mt], b, acc[mt][nt], 0, 0, 0);
      }
    }
  }

  float* ob = out + (size_t)t * 64 * 65536;
  float bias[2][4];
  #pragma unroll
  for (int mt = 0; mt < 2; ++mt)
    #pragma unroll
    for (int r = 0; r < 4; ++r) bias[mt][r] = bo[wm * 32 + mt * 16 + lg * 4 + r];
  #pragma unroll
  for (int mt = 0; mt < 2; ++mt)
    #pragma unroll
    for (int nt = 0; nt < 8; ++nt) {
      int ty = wn * 8 + nt;
      #pragma unroll
      for (int r = 0; r < 4; ++r) {
        int co = wm * 32 + mt * 16 + lg * 4 + r;
        float res = b2f(*(const unsigned short*)&yp[((ty + 1) * 18 + l15 + 1) * 72 + co]);
        ob[(size_t)co * 65536 + (size_t)(y0 + ty) * 256 + x0 + l15] = res + acc[mt][nt][r] + bias[mt][r];
      }
    }
}

// ---------------- launcher ----------------
extern "C" void kernel_launch(void* const* d_in, const int* in_sizes, int n_in,
                              void* d_out, int out_size, void* d_ws, size_t ws_size,
                              hipStream_t stream) {
  const float* x  = (const float*)d_in[0];
  const float* Wq = (const float*)d_in[1];
  const float* bq = (const float*)d_in[2];
  const float* Wk = (const float*)d_in[3];
  const float* bk = (const float*)d_in[4];
  const float* Wv = (const float*)d_in[5];
  const float* bv = (const float*)d_in[6];
  const float* Wo = (const float*)d_in[7];
  const float* bo = (const float*)d_in[8];
  float* out = (float*)d_out;

  char* ws = (char*)d_ws;
  bf16* wt  = (bf16*)(ws + 0);
  bf16* wot = (bf16*)(ws + 110592);
  bf16* q   = (bf16*)(ws + 262144);            // reused as y_img after qk_gemm
  bf16* k   = (bf16*)(ws + 67371008);
  bf16* vt  = (bf16*)(ws + 134479872);
  bf16* S   = (bf16*)(ws + 201588736);
  bf16* y   = (bf16*)(ws + 262144);
  // requires ws_size >= 335,806,464 bytes

  prep_w<<<216, 256, 0, stream>>>(Wq, Wk, Wv, Wo, wt, wot);
  qkv_conv<<<4096, 256, 0, stream>>>(x, wt, bq, bk, bv, q, k, vt);
  qk_gemm<<<4096, 256, 0, stream>>>(q, k, S);
  softmax_rows<<<16384, 256, 0, stream>>>(S);
  pv_gemm<<<2048, 256, 0, stream>>>(S, vt, y);
  out_conv<<<2048, 256, 0, stream>>>(y, wot, bo, out);
}

// Round 3
// 679.157 us; speedup vs baseline: 1.3424x; 1.3424x over previous
//
#include <hip/hip_runtime.h>
#include <hip/hip_bf16.h>
#include <stdint.h>

// Spatial local attention, MI355X bf16-MFMA implementation.
// Stages: prep_w -> qkv_conv(q,k,v coalesced) -> transpose_v -> qk_gemm(gload_lds)
//         -> softmax_rows -> pv_gemm(gload_lds) -> out_conv
//
// Workspace layout (bytes), total = 335,806,464 (~320.3 MiB):
//   [0        , 110592   ) Wqkv_t bf16 [9][192][32]
//   [110592   , 184320   ) Wo_t   bf16 [9][64][64]
//   [262144   , 67371008 ) q  bf16 [64][1024][512]   (reused as y_img bf16 [8][64][256][256])
//   [67371008 , 134479872) k  bf16 [64][1024][512]
//   [134479872, 201588736) v  bf16 [64][1024][512]   (dead after transpose_v; S overlaps)
//   [134479872, 268697600) S/P bf16 [64][1024][1024] (written by qk_gemm, after v is dead)
//   [268697600, 335806464) vt bf16 [64][512][1024]

using bf16 = __hip_bfloat16;
typedef short bf16x8 __attribute__((ext_vector_type(8)));
typedef float f32x4 __attribute__((ext_vector_type(4)));

#define AS1 __attribute__((address_space(1)))
#define AS3 __attribute__((address_space(3)))

__device__ __forceinline__ void gload_lds16(const void* g, void* l) {
  __builtin_amdgcn_global_load_lds((const AS1 unsigned int*)g, (AS3 unsigned int*)l, 16, 0, 0);
}
__device__ __forceinline__ float b2f(unsigned short u) {
  union { unsigned int i; float f; } x; x.i = ((unsigned)u) << 16; return x.f;
}
__device__ __forceinline__ unsigned short f2b(float f) {
  __hip_bfloat16 h = __float2bfloat16(f);
  return *reinterpret_cast<unsigned short*>(&h);
}

// ---------------- weight prep: f32 OIHW -> bf16 [step][co][ci] ----------------
__global__ __launch_bounds__(256) void prep_w(const float* __restrict__ Wq, const float* __restrict__ Wk,
                                              const float* __restrict__ Wv, const float* __restrict__ Wo,
                                              bf16* __restrict__ wt, bf16* __restrict__ wot) {
  int i = blockIdx.x * 256 + threadIdx.x;
  if (i < 9 * 192 * 32) {              // wt[s][co192][ci]
    int ci = i & 31, co192 = (i >> 5) % 192, s = i / 6144;
    int dy = s / 3, dx = s % 3;
    int proj = co192 >> 6, co = co192 & 63;
    const float* Ws = (proj == 0) ? Wq : ((proj == 1) ? Wk : Wv);
    wt[i] = __float2bfloat16(Ws[((co * 32 + ci) * 3 + dy) * 3 + dx]);
  }
  if (i < 9 * 64 * 64) {               // wot[s][co][ci]
    int ci = i & 63, co = (i >> 6) & 63, s = i >> 12;
    wot[i] = __float2bfloat16(Wo[((co * 64 + ci) * 3 + (s / 3)) * 3 + (s % 3)]);
  }
}

// ---------------- QKV windowed conv (per-window zero pad) ----------------
// block: 2 windows (128 px), M=192 (q|k|v x 64co), K = 9 steps x 32ci. 4 waves split M.
// Epilogue restages through LDS so all global stores are 16B-contiguous per lane.
__global__ __launch_bounds__(256) void qkv_conv(const float* __restrict__ x, const bf16* __restrict__ wt,
                                                const float* __restrict__ bq, const float* __restrict__ bk,
                                                const float* __restrict__ bv,
                                                bf16* __restrict__ qout, bf16* __restrict__ kout,
                                                bf16* __restrict__ vout) {
  __shared__ bf16 smem[192 * 136];     // union: xp [2*100][40] (8000 el) | outl [192][136]
  bf16* xp = smem;
  int tid = threadIdx.x, bid = blockIdx.x;
  int t = bid >> 9, g = bid & 511;
  int gy = g >> 4, gx0 = (g & 15) * 2;

  unsigned int* xp32 = (unsigned int*)xp;
  for (int i = tid; i < 4000; i += 256) xp32[i] = 0u;
  __syncthreads();
  const float* xb = x + (size_t)t * 32 * 65536;
  #pragma unroll
  for (int it = 0; it < 16; ++it) {
    int e = tid + it * 256;
    int ix = e & 7, win = (e >> 3) & 1, iy = (e >> 4) & 7, ci = e >> 7;
    float val = xb[(size_t)ci * 65536 + (gy * 8 + iy) * 256 + (gx0 + win) * 8 + ix];
    xp[(win * 100 + (iy + 1) * 10 + (ix + 1)) * 40 + ci] = __float2bfloat16(val);
  }
  __syncthreads();

  int wv = tid >> 6, l = tid & 63, l15 = l & 15, lg = l >> 4;
  f32x4 z4 = {0.f, 0.f, 0.f, 0.f};
  f32x4 acc[3][8];
  for (int i = 0; i < 3; ++i) for (int j = 0; j < 8; ++j) acc[i][j] = z4;

  #pragma unroll
  for (int s = 0; s < 9; ++s) {
    const int dy = s / 3, dx = s % 3;
    bf16x8 a[3];
    #pragma unroll
    for (int mt = 0; mt < 3; ++mt)
      a[mt] = *(const bf16x8*)&wt[((size_t)s * 192 + wv * 48 + mt * 16 + l15) * 32 + lg * 8];
    #pragma unroll
    for (int nt = 0; nt < 8; ++nt) {
      int n = nt * 16 + l15;
      int win = n >> 6, px = n & 63;
      int iy = px >> 3, ix = px & 7;
      bf16x8 b = *(const bf16x8*)&xp[(win * 100 + (iy + dy) * 10 + (ix + dx)) * 40 + lg * 8];
      #pragma unroll
      for (int mt = 0; mt < 3; ++mt)
        acc[mt][nt] = __builtin_amdgcn_mfma_f32_16x16x32_bf16(a[mt], b, acc[mt][nt], 0, 0, 0);
    }
  }

  // epilogue pass 1: acc+bias -> outl[co192][n], stride 136
  __syncthreads();                     // xp reads complete; reuse smem as outl
  bf16* outl = smem;
  #pragma unroll
  for (int mt = 0; mt < 3; ++mt) {
    int c0 = wv * 48 + mt * 16 + lg * 4;
    int proj = c0 >> 6;
    const float* bptr = (proj == 0) ? bq : ((proj == 1) ? bk : bv);
    float bias[4];
    #pragma unroll
    for (int r = 0; r < 4; ++r) bias[r] = bptr[(c0 + r) & 63];
    #pragma unroll
    for (int nt = 0; nt < 8; ++nt) {
      int n = nt * 16 + l15;
      #pragma unroll
      for (int r = 0; r < 4; ++r)
        outl[(c0 + r) * 136 + n] = __float2bfloat16(acc[mt][nt][r] + bias[r]);
    }
  }
  __syncthreads();

  // epilogue pass 2: coalesced 16B stores. chunk c: [win(1)|head(3)|d8(6)] per proj.
  #pragma unroll
  for (int proj = 0; proj < 3; ++proj) {
    bf16* dst = (proj == 0) ? qout : ((proj == 1) ? kout : vout);
    #pragma unroll
    for (int pass = 0; pass < 4; ++pass) {
      int c = pass * 256 + tid;
      int d8 = c & 63, head = (c >> 6) & 7, wn2 = c >> 9;
      int jj = d8 >> 3, px0 = (d8 & 7) * 8;
      bf16x8 val = *(const bf16x8*)&outl[(proj * 64 + head * 8 + jj) * 136 + wn2 * 64 + px0];
      size_t gwin = (size_t)gy * 32 + gx0 + wn2;
      *(bf16x8*)&dst[((size_t)(t * 8 + head) * 1024 + gwin) * 512 + d8 * 8] = val;
    }
  }
}

// ---------------- V transpose: [bh][win][d] -> [bh][d][win], 64x64 LDS tiles ----------------
__global__ __launch_bounds__(256) void transpose_v(const bf16* __restrict__ v, bf16* __restrict__ vt) {
  __shared__ bf16 tl[64 * 72];         // [d][win pad72]
  int tid = threadIdx.x, bid = blockIdx.x;
  int bh = bid >> 7, wtile = (bid >> 3) & 15, dtile = bid & 7;
  int w0 = wtile * 64, d0 = dtile * 64;
  const bf16* vb = v + ((size_t)bh * 1024 + w0) * 512 + d0;
  int win_l = tid >> 2, dseg = (tid & 3) * 16;
  bf16x8 x0 = *(const bf16x8*)&vb[(size_t)win_l * 512 + dseg];
  bf16x8 x1 = *(const bf16x8*)&vb[(size_t)win_l * 512 + dseg + 8];
  #pragma unroll
  for (int j = 0; j < 8; ++j) {
    *(short*)&tl[(dseg + j) * 72 + win_l] = x0[j];
    *(short*)&tl[(dseg + 8 + j) * 72 + win_l] = x1[j];
  }
  __syncthreads();
  int d_l = tid >> 2, wseg = (tid & 3) * 16;
  bf16x8 y0 = *(const bf16x8*)&tl[d_l * 72 + wseg];
  bf16x8 y1 = *(const bf16x8*)&tl[d_l * 72 + wseg + 8];
  bf16* vtb = vt + ((size_t)bh * 512 + d0 + d_l) * 1024 + w0 + wseg;
  *(bf16x8*)&vtb[0] = y0;
  *(bf16x8*)&vtb[8] = y1;
}

// ---------------- batched QK^T -> S bf16 (scaled), global_load_lds staging ----------------
__global__ __launch_bounds__(256) void qk_gemm(const bf16* __restrict__ q, const bf16* __restrict__ k,
                                               bf16* __restrict__ S) {
  __shared__ bf16 Atile[128 * 32];
  __shared__ bf16 Btile[128 * 32];
  int tid = threadIdx.x;
  int bid = (blockIdx.x & 7) * 512 + (blockIdx.x >> 3);    // XCD swizzle (4096 % 8 == 0)
  int batch = bid >> 6, tm = (bid >> 3) & 7, tn = bid & 7;
  const bf16* Qb = q + (size_t)batch * 1024 * 512 + (size_t)tm * 128 * 512;
  const bf16* Kb = k + (size_t)batch * 1024 * 512 + (size_t)tn * 128 * 512;
  int wv = tid >> 6, l = tid & 63, l15 = l & 15, lg = l >> 4;
  int wm = wv & 1, wn = wv >> 1;
  int srow = tid >> 2, koff = (tid & 3) * 8;
  f32x4 z4 = {0.f, 0.f, 0.f, 0.f};
  f32x4 acc[4][4];
  for (int i = 0; i < 4; ++i) for (int j = 0; j < 4; ++j) acc[i][j] = z4;

  for (int s = 0; s < 16; ++s) {
    __syncthreads();
    #pragma unroll
    for (int half = 0; half < 2; ++half) {
      size_t row = half * 64 + srow;
      gload_lds16(Qb + row * 512 + s * 32 + koff, (char*)Atile + half * 4096 + wv * 1024);
      gload_lds16(Kb + row * 512 + s * 32 + koff, (char*)Btile + half * 4096 + wv * 1024);
    }
    __syncthreads();
    bf16x8 a[4], b[4];
    #pragma unroll
    for (int i = 0; i < 4; ++i) {
      a[i] = *(const bf16x8*)&Atile[(wm * 64 + i * 16 + l15) * 32 + lg * 8];
      b[i] = *(const bf16x8*)&Btile[(wn * 64 + i * 16 + l15) * 32 + lg * 8];
    }
    #pragma unroll
    for (int i = 0; i < 4; ++i)
      #pragma unroll
      for (int j = 0; j < 4; ++j)
        acc[i][j] = __builtin_amdgcn_mfma_f32_16x16x32_bf16(a[i], b[j], acc[i][j], 0, 0, 0);
  }

  const float SCALE = 0.04419417382415922f;  // 1/sqrt(512)
  bf16* Sb = S + (size_t)batch * 1024 * 1024;
  #pragma unroll
  for (int i = 0; i < 4; ++i)
    #pragma unroll
    for (int j = 0; j < 4; ++j)
      #pragma unroll
      for (int r = 0; r < 4; ++r) {
        int row = tm * 128 + wm * 64 + i * 16 + lg * 4 + r;
        int col = tn * 128 + wn * 64 + j * 16 + l15;
        Sb[(size_t)row * 1024 + col] = __float2bfloat16(acc[i][j][r] * SCALE);
      }
}

// ---------------- row softmax (in place, 1 wave per 1024-row) ----------------
__global__ __launch_bounds__(256) void softmax_rows(bf16* __restrict__ S) {
  int l = threadIdx.x & 63;
  size_t row = (size_t)blockIdx.x * 4 + (threadIdx.x >> 6);
  bf16* p = S + row * 1024 + l * 16;
  bf16x8 s0 = *(const bf16x8*)p;
  bf16x8 s1 = *(const bf16x8*)(p + 8);
  float f[16];
  #pragma unroll
  for (int i = 0; i < 8; ++i) { f[i] = b2f((unsigned short)s0[i]); f[8 + i] = b2f((unsigned short)s1[i]); }
  float m = f[0];
  #pragma unroll
  for (int i = 1; i < 16; ++i) m = fmaxf(m, f[i]);
  for (int d = 1; d < 64; d <<= 1) m = fmaxf(m, __shfl_xor(m, d));
  float sum = 0.f;
  #pragma unroll
  for (int i = 0; i < 16; ++i) { f[i] = __expf(f[i] - m); sum += f[i]; }
  for (int d = 1; d < 64; d <<= 1) sum += __shfl_xor(sum, d);
  float r = 1.0f / sum;
  bf16x8 o0, o1;
  #pragma unroll
  for (int i = 0; i < 8; ++i) { o0[i] = (short)f2b(f[i] * r); o1[i] = (short)f2b(f[8 + i] * r); }
  *(bf16x8*)p = o0;
  *(bf16x8*)(p + 8) = o1;
}

// ---------------- batched PV (B = Vt rows) -> y image layout, LDS-restaged epilogue ----------------
__global__ __launch_bounds__(256) void pv_gemm(const bf16* __restrict__ P, const bf16* __restrict__ vt,
                                               bf16* __restrict__ y) {
  __shared__ char pvsmem[34816];       // union: Atile(8K)+Btile(8K) | yl [128][136] bf16
  bf16* Atile = (bf16*)pvsmem;
  bf16* Btile = (bf16*)(pvsmem + 8192);
  bf16* yl = (bf16*)pvsmem;
  int tid = threadIdx.x;
  int bid = (blockIdx.x & 7) * 256 + (blockIdx.x >> 3);    // XCD swizzle (2048 % 8 == 0)
  int batch = bid >> 5, bq = (bid >> 2) & 7, bd = bid & 3;
  const bf16* Pb = P + (size_t)batch * 1024 * 1024 + (size_t)bq * 128 * 1024;
  const bf16* Vb = vt + (size_t)batch * 512 * 1024 + (size_t)bd * 128 * 1024;
  int wv = tid >> 6, l = tid & 63, l15 = l & 15, lg = l >> 4;
  int wm = wv & 1, wn = wv >> 1;
  int srow = tid >> 2, koff = (tid & 3) * 8;
  f32x4 z4 = {0.f, 0.f, 0.f, 0.f};
  f32x4 acc[4][4];
  for (int i = 0; i < 4; ++i) for (int j = 0; j < 4; ++j) acc[i][j] = z4;

  for (int s = 0; s < 32; ++s) {
    __syncthreads();
    #pragma unroll
    for (int half = 0; half < 2; ++half) {
      size_t row = half * 64 + srow;
      gload_lds16(Pb + row * 1024 + s * 32 + koff, (char*)Atile + half * 4096 + wv * 1024);
      gload_lds16(Vb + row * 1024 + s * 32 + koff, (char*)Btile + half * 4096 + wv * 1024);
    }
    __syncthreads();
    bf16x8 a[4], b[4];
    #pragma unroll
    for (int i = 0; i < 4; ++i) {
      a[i] = *(const bf16x8*)&Atile[(wm * 64 + i * 16 + l15) * 32 + lg * 8];
      b[i] = *(const bf16x8*)&Btile[(wn * 64 + i * 16 + l15) * 32 + lg * 8];
    }
    #pragma unroll
    for (int i = 0; i < 4; ++i)
      #pragma unroll
      for (int j = 0; j < 4; ++j)
        acc[i][j] = __builtin_amdgcn_mfma_f32_16x16x32_bf16(a[i], b[j], acc[i][j], 0, 0, 0);
  }

  // epilogue pass 1: acc -> yl[win_local][d_local]
  __syncthreads();
  #pragma unroll
  for (int i = 0; i < 4; ++i)
    #pragma unroll
    for (int j = 0; j < 4; ++j)
      #pragma unroll
      for (int r = 0; r < 4; ++r)
        yl[(wm * 64 + i * 16 + lg * 4 + r) * 136 + wn * 64 + j * 16 + l15] =
            __float2bfloat16(acc[i][j][r]);
  __syncthreads();

  // epilogue pass 2: coalesced stores; chunk c = [jj(1)|py(3)|gy_l(2)|gx(5)]
  int t = batch >> 3, h = batch & 7;
  #pragma unroll
  for (int pass = 0; pass < 8; ++pass) {
    int c = pass * 256 + tid;
    int gx = c & 31, gy_l = (c >> 5) & 3, py = (c >> 7) & 7, jj = c >> 10;
    int win_l = gy_l * 32 + gx, d_l = jj * 64 + py * 8;
    bf16x8 val = *(const bf16x8*)&yl[win_l * 136 + d_l];
    int gyy = bq * 4 + gy_l;
    int jj_g = bd * 2 + jj;
    *(bf16x8*)&y[((size_t)(t * 64 + h * 8 + jj_g) * 256 + gyy * 8 + py) * 256 + gx * 8] = val;
  }
}

// ---------------- final full-image conv + residual -> f32 out ----------------
__global__ __launch_bounds__(256) void out_conv(const bf16* __restrict__ yimg, const bf16* __restrict__ wot,
                                                const float* __restrict__ bo, float* __restrict__ out) {
  __shared__ bf16 yp[324 * 72];        // [py*18+px][ci pad72]
  int tid = threadIdx.x, bid = blockIdx.x;
  int t = bid >> 8, tile = bid & 255;
  int y0 = (tile >> 4) * 16, x0 = (tile & 15) * 16;
  const bf16* yb = yimg + (size_t)t * 64 * 65536;

  for (int e = tid; e < 18 * 18 * 64; e += 256) {
    int ppx = e % 18; int rem = e / 18; int ppy = rem % 18; int ci = rem / 18;
    int gy = y0 + ppy - 1, gx = x0 + ppx - 1;
    unsigned short val = 0;
    if ((unsigned)gy < 256u && (unsigned)gx < 256u)
      val = *(const unsigned short*)&yb[(size_t)ci * 65536 + gy * 256 + gx];
    *(unsigned short*)&yp[(ppy * 18 + ppx) * 72 + ci] = val;
  }
  __syncthreads();

  int wv = tid >> 6, l = tid & 63, l15 = l & 15, lg = l >> 4;
  int wm = wv & 1, wn = wv >> 1;
  f32x4 z4 = {0.f, 0.f, 0.f, 0.f};
  f32x4 acc[2][8];
  for (int i = 0; i < 2; ++i) for (int j = 0; j < 8; ++j) acc[i][j] = z4;

  #pragma unroll
  for (int s9 = 0; s9 < 9; ++s9) {
    const int dy = s9 / 3, dx = s9 % 3;
    #pragma unroll
    for (int half = 0; half < 2; ++half) {
      bf16x8 a[2];
      #pragma unroll
      for (int mt = 0; mt < 2; ++mt)
        a[mt] = *(const bf16x8*)&wot[((size_t)s9 * 64 + wm * 32 + mt * 16 + l15) * 64 + half * 32 + lg * 8];
      #pragma unroll
      for (int nt = 0; nt < 8; ++nt) {
        int ty = wn * 8 + nt;
        bf16x8 b = *(const bf16x8*)&yp[((ty + dy) * 18 + l15 + dx) * 72 + half * 32 + lg * 8];
        #pragma unroll
        for (int mt = 0; mt < 2; ++mt)
          acc[mt][nt] = __builtin_amdgcn_mfma_f32_16x16x32_bf16(a[mt], b, acc[mt][nt], 0, 0, 0);
      }
    }
  }

  float* ob = out + (size_t)t * 64 * 65536;
  float bias[2][4];
  #pragma unroll
  for (int mt = 0; mt < 2; ++mt)
    #pragma unroll
    for (int r = 0; r < 4; ++r) bias[mt][r] = bo[wm * 32 + mt * 16 + lg * 4 + r];
  #pragma unroll
  for (int mt = 0; mt < 2; ++mt)
    #pragma unroll
    for (int nt = 0; nt < 8; ++nt) {
      int ty = wn * 8 + nt;
      #pragma unroll
      for (int r = 0; r < 4; ++r) {
        int co = wm * 32 + mt * 16 + lg * 4 + r;
        float res = b2f(*(const unsigned short*)&yp[((ty + 1) * 18 + l15 + 1) * 72 + co]);
        ob[(size_t)co * 65536 + (size_t)(y0 + ty) * 256 + x0 + l15] = res + acc[mt][nt][r] + bias[mt][r];
      }
    }
}

// ---------------- launcher ----------------
extern "C" void kernel_launch(void* const* d_in, const int* in_sizes, int n_in,
                              void* d_out, int out_size, void* d_ws, size_t ws_size,
                              hipStream_t stream) {
  const float* x  = (const float*)d_in[0];
  const float* Wq = (const float*)d_in[1];
  const float* bq = (const float*)d_in[2];
  const float* Wk = (const float*)d_in[3];
  const float* bk = (const float*)d_in[4];
  const float* Wv = (const float*)d_in[5];
  const float* bv = (const float*)d_in[6];
  const float* Wo = (const float*)d_in[7];
  const float* bo = (const float*)d_in[8];
  float* out = (float*)d_out;

  char* ws = (char*)d_ws;
  bf16* wt  = (bf16*)(ws + 0);
  bf16* wot = (bf16*)(ws + 110592);
  bf16* q   = (bf16*)(ws + 262144);              // reused as y_img after qk_gemm
  bf16* k   = (bf16*)(ws + 67371008);
  bf16* v   = (bf16*)(ws + 134479872);           // dead after transpose_v
  bf16* S   = (bf16*)(ws + 134479872);           // overlaps v (written after v dead)
  bf16* vt  = (bf16*)(ws + 268697600);
  bf16* y   = (bf16*)(ws + 262144);
  // requires ws_size >= 335,806,464 bytes

  prep_w<<<216, 256, 0, stream>>>(Wq, Wk, Wv, Wo, wt, wot);
  qkv_conv<<<4096, 256, 0, stream>>>(x, wt, bq, bk, bv, q, k, v);
  transpose_v<<<8192, 256, 0, stream>>>(v, vt);
  qk_gemm<<<4096, 256, 0, stream>>>(q, k, S);
  softmax_rows<<<16384, 256, 0, stream>>>(S);
  pv_gemm<<<2048, 256, 0, stream>>>(S, vt, y);
  out_conv<<<2048, 256, 0, stream>>>(y, wot, bo, out);
}

// Round 4
// 550.145 us; speedup vs baseline: 1.6572x; 1.2345x over previous
//
#include <hip/hip_runtime.h>
#include <hip/hip_bf16.h>
#include <stdint.h>

// Spatial local attention, MI355X bf16-MFMA implementation.
// Stages: prep_w -> qkv_conv -> transpose_v(d-permute) -> qk_gemm -> softmax_rows
//         -> pv_gemm(channels-last y) -> out_conv(channels-last staging)
//
// Feature-dim permutation: attention feature index d' = pyix*8 + jj (jj = co within head,
// pyix = window-local pixel). Q/K keep d = jj*64+pyix (inner product invariant);
// Vt rows are written at d' so PV output columns come out pixel-major -> channels-last y.
//
// Workspace layout (bytes), total = 335,806,464 (~320.3 MiB):
//   [0        , 110592   ) Wqkv_t bf16 [9][192][32]
//   [110592   , 184320   ) Wo_t   bf16 [9][64][64]
//   [262144   , 67371008 ) q  bf16 [64][1024][512]   (reused as y_img bf16 [8][256][256][64] channels-last)
//   [67371008 , 134479872) k  bf16 [64][1024][512]
//   [134479872, 201588736) v  bf16 [64][1024][512]   (dead after transpose_v; S overlaps)
//   [134479872, 268697600) S/P bf16 [64][1024][1024]
//   [268697600, 335806464) vt bf16 [64][512][1024]   (rows indexed by d')

using bf16 = __hip_bfloat16;
typedef short bf16x8 __attribute__((ext_vector_type(8)));
typedef float f32x4 __attribute__((ext_vector_type(4)));

#define AS1 __attribute__((address_space(1)))
#define AS3 __attribute__((address_space(3)))

__device__ __forceinline__ void gload_lds16(const void* g, void* l) {
  __builtin_amdgcn_global_load_lds((const AS1 unsigned int*)g, (AS3 unsigned int*)l, 16, 0, 0);
}
__device__ __forceinline__ float b2f(unsigned short u) {
  union { unsigned int i; float f; } x; x.i = ((unsigned)u) << 16; return x.f;
}
__device__ __forceinline__ unsigned short f2b(float f) {
  __hip_bfloat16 h = __float2bfloat16(f);
  return *reinterpret_cast<unsigned short*>(&h);
}

// ---------------- weight prep: f32 OIHW -> bf16 [step][co][ci] ----------------
__global__ __launch_bounds__(256) void prep_w(const float* __restrict__ Wq, const float* __restrict__ Wk,
                                              const float* __restrict__ Wv, const float* __restrict__ Wo,
                                              bf16* __restrict__ wt, bf16* __restrict__ wot) {
  int i = blockIdx.x * 256 + threadIdx.x;
  if (i < 9 * 192 * 32) {              // wt[s][co192][ci]
    int ci = i & 31, co192 = (i >> 5) % 192, s = i / 6144;
    int dy = s / 3, dx = s % 3;
    int proj = co192 >> 6, co = co192 & 63;
    const float* Ws = (proj == 0) ? Wq : ((proj == 1) ? Wk : Wv);
    wt[i] = __float2bfloat16(Ws[((co * 32 + ci) * 3 + dy) * 3 + dx]);
  }
  if (i < 9 * 64 * 64) {               // wot[s][co][ci]
    int ci = i & 63, co = (i >> 6) & 63, s = i >> 12;
    wot[i] = __float2bfloat16(Wo[((co * 64 + ci) * 3 + (s / 3)) * 3 + (s % 3)]);
  }
}

// ---------------- QKV windowed conv (per-window zero pad) ----------------
__global__ __launch_bounds__(256) void qkv_conv(const float* __restrict__ x, const bf16* __restrict__ wt,
                                                const float* __restrict__ bq, const float* __restrict__ bk,
                                                const float* __restrict__ bv,
                                                bf16* __restrict__ qout, bf16* __restrict__ kout,
                                                bf16* __restrict__ vout) {
  __shared__ bf16 smem[192 * 136];     // union: xp [2*100][40] (8000 el) | outl [192][136]
  bf16* xp = smem;
  int tid = threadIdx.x, bid = blockIdx.x;
  int t = bid >> 9, g = bid & 511;
  int gy = g >> 4, gx0 = (g & 15) * 2;

  unsigned int* xp32 = (unsigned int*)xp;
  for (int i = tid; i < 4000; i += 256) xp32[i] = 0u;
  __syncthreads();
  const float* xb = x + (size_t)t * 32 * 65536;
  #pragma unroll
  for (int it = 0; it < 16; ++it) {
    int e = tid + it * 256;
    int ix = e & 7, win = (e >> 3) & 1, iy = (e >> 4) & 7, ci = e >> 7;
    float val = xb[(size_t)ci * 65536 + (gy * 8 + iy) * 256 + (gx0 + win) * 8 + ix];
    xp[(win * 100 + (iy + 1) * 10 + (ix + 1)) * 40 + ci] = __float2bfloat16(val);
  }
  __syncthreads();

  int wv = tid >> 6, l = tid & 63, l15 = l & 15, lg = l >> 4;
  f32x4 z4 = {0.f, 0.f, 0.f, 0.f};
  f32x4 acc[3][8];
  for (int i = 0; i < 3; ++i) for (int j = 0; j < 8; ++j) acc[i][j] = z4;

  #pragma unroll
  for (int s = 0; s < 9; ++s) {
    const int dy = s / 3, dx = s % 3;
    bf16x8 a[3];
    #pragma unroll
    for (int mt = 0; mt < 3; ++mt)
      a[mt] = *(const bf16x8*)&wt[((size_t)s * 192 + wv * 48 + mt * 16 + l15) * 32 + lg * 8];
    #pragma unroll
    for (int nt = 0; nt < 8; ++nt) {
      int n = nt * 16 + l15;
      int win = n >> 6, px = n & 63;
      int iy = px >> 3, ix = px & 7;
      bf16x8 b = *(const bf16x8*)&xp[(win * 100 + (iy + dy) * 10 + (ix + dx)) * 40 + lg * 8];
      #pragma unroll
      for (int mt = 0; mt < 3; ++mt)
        acc[mt][nt] = __builtin_amdgcn_mfma_f32_16x16x32_bf16(a[mt], b, acc[mt][nt], 0, 0, 0);
    }
  }

  // epilogue pass 1: acc+bias -> outl[co192][n], stride 136
  __syncthreads();
  bf16* outl = smem;
  #pragma unroll
  for (int mt = 0; mt < 3; ++mt) {
    int c0 = wv * 48 + mt * 16 + lg * 4;
    int proj = c0 >> 6;
    const float* bptr = (proj == 0) ? bq : ((proj == 1) ? bk : bv);
    float bias[4];
    #pragma unroll
    for (int r = 0; r < 4; ++r) bias[r] = bptr[(c0 + r) & 63];
    #pragma unroll
    for (int nt = 0; nt < 8; ++nt) {
      int n = nt * 16 + l15;
      #pragma unroll
      for (int r = 0; r < 4; ++r)
        outl[(c0 + r) * 136 + n] = __float2bfloat16(acc[mt][nt][r] + bias[r]);
    }
  }
  __syncthreads();

  // epilogue pass 2: coalesced 16B stores. chunk c: [win(1)|head(3)|d8(6)] per proj.
  #pragma unroll
  for (int proj = 0; proj < 3; ++proj) {
    bf16* dst = (proj == 0) ? qout : ((proj == 1) ? kout : vout);
    #pragma unroll
    for (int pass = 0; pass < 4; ++pass) {
      int c = pass * 256 + tid;
      int d8 = c & 63, head = (c >> 6) & 7, wn2 = c >> 9;
      int jj = d8 >> 3, px0 = (d8 & 7) * 8;
      bf16x8 val = *(const bf16x8*)&outl[(proj * 64 + head * 8 + jj) * 136 + wn2 * 64 + px0];
      size_t gwin = (size_t)gy * 32 + gx0 + wn2;
      *(bf16x8*)&dst[((size_t)(t * 8 + head) * 1024 + gwin) * 512 + d8 * 8] = val;
    }
  }
}

// ---------------- V transpose + d-permute: [bh][win][d=jj*64+pyix] -> [bh][d'=pyix*8+jj][win] ----------------
__global__ __launch_bounds__(256) void transpose_v(const bf16* __restrict__ v, bf16* __restrict__ vt) {
  __shared__ bf16 tl[64 * 72];         // [d_local][win pad72]
  int tid = threadIdx.x, bid = blockIdx.x;
  int bh = bid >> 7, wtile = (bid >> 3) & 15, dtile = bid & 7;   // dtile == jj
  int w0 = wtile * 64, d0 = dtile * 64;
  const bf16* vb = v + ((size_t)bh * 1024 + w0) * 512 + d0;
  int win_l = tid >> 2, dseg = (tid & 3) * 16;
  bf16x8 x0 = *(const bf16x8*)&vb[(size_t)win_l * 512 + dseg];
  bf16x8 x1 = *(const bf16x8*)&vb[(size_t)win_l * 512 + dseg + 8];
  #pragma unroll
  for (int j = 0; j < 8; ++j) {
    *(short*)&tl[(dseg + j) * 72 + win_l] = x0[j];
    *(short*)&tl[(dseg + 8 + j) * 72 + win_l] = x1[j];
  }
  __syncthreads();
  int d_l = tid >> 2, wseg = (tid & 3) * 16;   // d_l == pyix
  bf16x8 y0 = *(const bf16x8*)&tl[d_l * 72 + wseg];
  bf16x8 y1 = *(const bf16x8*)&tl[d_l * 72 + wseg + 8];
  bf16* vtb = vt + ((size_t)bh * 512 + d_l * 8 + dtile) * 1024 + w0 + wseg;
  *(bf16x8*)&vtb[0] = y0;
  *(bf16x8*)&vtb[8] = y1;
}

// ---------------- batched QK^T -> S bf16 (scaled), global_load_lds staging ----------------
__global__ __launch_bounds__(256) void qk_gemm(const bf16* __restrict__ q, const bf16* __restrict__ k,
                                               bf16* __restrict__ S) {
  __shared__ bf16 Atile[128 * 32];
  __shared__ bf16 Btile[128 * 32];
  int tid = threadIdx.x;
  int bid = (blockIdx.x & 7) * 512 + (blockIdx.x >> 3);    // XCD swizzle (4096 % 8 == 0)
  int batch = bid >> 6, tm = (bid >> 3) & 7, tn = bid & 7;
  const bf16* Qb = q + (size_t)batch * 1024 * 512 + (size_t)tm * 128 * 512;
  const bf16* Kb = k + (size_t)batch * 1024 * 512 + (size_t)tn * 128 * 512;
  int wv = tid >> 6, l = tid & 63, l15 = l & 15, lg = l >> 4;
  int wm = wv & 1, wn = wv >> 1;
  int srow = tid >> 2, koff = (tid & 3) * 8;
  f32x4 z4 = {0.f, 0.f, 0.f, 0.f};
  f32x4 acc[4][4];
  for (int i = 0; i < 4; ++i) for (int j = 0; j < 4; ++j) acc[i][j] = z4;

  for (int s = 0; s < 16; ++s) {
    __syncthreads();
    #pragma unroll
    for (int half = 0; half < 2; ++half) {
      size_t row = half * 64 + srow;
      gload_lds16(Qb + row * 512 + s * 32 + koff, (char*)Atile + half * 4096 + wv * 1024);
      gload_lds16(Kb + row * 512 + s * 32 + koff, (char*)Btile + half * 4096 + wv * 1024);
    }
    __syncthreads();
    bf16x8 a[4], b[4];
    #pragma unroll
    for (int i = 0; i < 4; ++i) {
      a[i] = *(const bf16x8*)&Atile[(wm * 64 + i * 16 + l15) * 32 + lg * 8];
      b[i] = *(const bf16x8*)&Btile[(wn * 64 + i * 16 + l15) * 32 + lg * 8];
    }
    #pragma unroll
    for (int i = 0; i < 4; ++i)
      #pragma unroll
      for (int j = 0; j < 4; ++j)
        acc[i][j] = __builtin_amdgcn_mfma_f32_16x16x32_bf16(a[i], b[j], acc[i][j], 0, 0, 0);
  }

  const float SCALE = 0.04419417382415922f;  // 1/sqrt(512)
  bf16* Sb = S + (size_t)batch * 1024 * 1024;
  #pragma unroll
  for (int i = 0; i < 4; ++i)
    #pragma unroll
    for (int j = 0; j < 4; ++j)
      #pragma unroll
      for (int r = 0; r < 4; ++r) {
        int row = tm * 128 + wm * 64 + i * 16 + lg * 4 + r;
        int col = tn * 128 + wn * 64 + j * 16 + l15;
        Sb[(size_t)row * 1024 + col] = __float2bfloat16(acc[i][j][r] * SCALE);
      }
}

// ---------------- row softmax (in place, 1 wave per 1024-row) ----------------
__global__ __launch_bounds__(256) void softmax_rows(bf16* __restrict__ S) {
  int l = threadIdx.x & 63;
  size_t row = (size_t)blockIdx.x * 4 + (threadIdx.x >> 6);
  bf16* p = S + row * 1024 + l * 16;
  bf16x8 s0 = *(const bf16x8*)p;
  bf16x8 s1 = *(const bf16x8*)(p + 8);
  float f[16];
  #pragma unroll
  for (int i = 0; i < 8; ++i) { f[i] = b2f((unsigned short)s0[i]); f[8 + i] = b2f((unsigned short)s1[i]); }
  float m = f[0];
  #pragma unroll
  for (int i = 1; i < 16; ++i) m = fmaxf(m, f[i]);
  for (int d = 1; d < 64; d <<= 1) m = fmaxf(m, __shfl_xor(m, d));
  float sum = 0.f;
  #pragma unroll
  for (int i = 0; i < 16; ++i) { f[i] = __expf(f[i] - m); sum += f[i]; }
  for (int d = 1; d < 64; d <<= 1) sum += __shfl_xor(sum, d);
  float r = 1.0f / sum;
  bf16x8 o0, o1;
  #pragma unroll
  for (int i = 0; i < 8; ++i) { o0[i] = (short)f2b(f[i] * r); o1[i] = (short)f2b(f[8 + i] * r); }
  *(bf16x8*)p = o0;
  *(bf16x8*)(p + 8) = o1;
}

// ---------------- batched PV (B = Vt rows at d') -> channels-last y image ----------------
// y_img[t][Y][X][co], co = h*8+jj. Block owns d' range [bd*128, bd*128+128) =
// pyix in [bd*16, bd*16+16) x all jj -> 16B store per (win, pyix).
__global__ __launch_bounds__(256) void pv_gemm(const bf16* __restrict__ P, const bf16* __restrict__ vt,
                                               bf16* __restrict__ y) {
  __shared__ char pvsmem[34816];       // union: Atile(8K)+Btile(8K) | yl [128][136] bf16
  bf16* Atile = (bf16*)pvsmem;
  bf16* Btile = (bf16*)(pvsmem + 8192);
  bf16* yl = (bf16*)pvsmem;
  int tid = threadIdx.x;
  int bid = (blockIdx.x & 7) * 256 + (blockIdx.x >> 3);    // XCD swizzle (2048 % 8 == 0)
  int batch = bid >> 5, bq = (bid >> 2) & 7, bd = bid & 3;
  const bf16* Pb = P + (size_t)batch * 1024 * 1024 + (size_t)bq * 128 * 1024;
  const bf16* Vb = vt + (size_t)batch * 512 * 1024 + (size_t)bd * 128 * 1024;
  int wv = tid >> 6, l = tid & 63, l15 = l & 15, lg = l >> 4;
  int wm = wv & 1, wn = wv >> 1;
  int srow = tid >> 2, koff = (tid & 3) * 8;
  f32x4 z4 = {0.f, 0.f, 0.f, 0.f};
  f32x4 acc[4][4];
  for (int i = 0; i < 4; ++i) for (int j = 0; j < 4; ++j) acc[i][j] = z4;

  for (int s = 0; s < 32; ++s) {
    __syncthreads();
    #pragma unroll
    for (int half = 0; half < 2; ++half) {
      size_t row = half * 64 + srow;
      gload_lds16(Pb + row * 1024 + s * 32 + koff, (char*)Atile + half * 4096 + wv * 1024);
      gload_lds16(Vb + row * 1024 + s * 32 + koff, (char*)Btile + half * 4096 + wv * 1024);
    }
    __syncthreads();
    bf16x8 a[4], b[4];
    #pragma unroll
    for (int i = 0; i < 4; ++i) {
      a[i] = *(const bf16x8*)&Atile[(wm * 64 + i * 16 + l15) * 32 + lg * 8];
      b[i] = *(const bf16x8*)&Btile[(wn * 64 + i * 16 + l15) * 32 + lg * 8];
    }
    #pragma unroll
    for (int i = 0; i < 4; ++i)
      #pragma unroll
      for (int j = 0; j < 4; ++j)
        acc[i][j] = __builtin_amdgcn_mfma_f32_16x16x32_bf16(a[i], b[j], acc[i][j], 0, 0, 0);
  }

  // epilogue pass 1: acc -> yl[win_local][d'_local]
  __syncthreads();
  #pragma unroll
  for (int i = 0; i < 4; ++i)
    #pragma unroll
    for (int j = 0; j < 4; ++j)
      #pragma unroll
      for (int r = 0; r < 4; ++r)
        yl[(wm * 64 + i * 16 + lg * 4 + r) * 136 + wn * 64 + j * 16 + l15] =
            __float2bfloat16(acc[i][j][r]);
  __syncthreads();

  // epilogue pass 2: channels-last stores; chunk c = [win_l(7b)|pyix_l(4b)] -> 16B (jj 0..7)
  int t = batch >> 3, h = batch & 7;
  #pragma unroll
  for (int pass = 0; pass < 8; ++pass) {
    int c = pass * 256 + tid;
    int pyix_l = c & 15, win_l = c >> 4;
    bf16x8 val = *(const bf16x8*)&yl[win_l * 136 + pyix_l * 8];
    int win = bq * 128 + win_l;
    int gy = win >> 5, gx = win & 31;
    int pyix = bd * 16 + pyix_l;
    int Y = gy * 8 + (pyix >> 3), X = gx * 8 + (pyix & 7);
    *(bf16x8*)&y[(((size_t)t * 256 + Y) * 256 + X) * 64 + h * 8] = val;
  }
}

// ---------------- final full-image conv + residual -> f32 out ----------------
// y_img channels-last: halo staging is 16B-vectorized (8 lanes per pixel).
__global__ __launch_bounds__(256) void out_conv(const bf16* __restrict__ yimg, const bf16* __restrict__ wot,
                                                const float* __restrict__ bo, float* __restrict__ out) {
  __shared__ bf16 yp[324 * 76];        // [py*18+px][ci pad76]
  int tid = threadIdx.x, bid = blockIdx.x;
  int t = bid >> 8, tile = bid & 255;
  int y0 = (tile >> 4) * 16, x0 = (tile & 15) * 16;
  const bf16* yb = yimg + (size_t)t * 256 * 256 * 64;

  for (int e = tid; e < 324 * 8; e += 256) {
    int seg = e & 7, pos = e >> 3;
    int ppx = pos % 18, ppy = pos / 18;
    int gy = y0 + ppy - 1, gx = x0 + ppx - 1;
    bf16x8 val = {0, 0, 0, 0, 0, 0, 0, 0};
    if ((unsigned)gy < 256u && (unsigned)gx < 256u)
      val = *(const bf16x8*)&yb[((size_t)gy * 256 + gx) * 64 + seg * 8];
    *(bf16x8*)&yp[pos * 76 + seg * 8] = val;
  }
  __syncthreads();

  int wv = tid >> 6, l = tid & 63, l15 = l & 15, lg = l >> 4;
  int wm = wv & 1, wn = wv >> 1;
  f32x4 z4 = {0.f, 0.f, 0.f, 0.f};
  f32x4 acc[2][8];
  for (int i = 0; i < 2; ++i) for (int j = 0; j < 8; ++j) acc[i][j] = z4;

  #pragma unroll
  for (int s9 = 0; s9 < 9; ++s9) {
    const int dy = s9 / 3, dx = s9 % 3;
    #pragma unroll
    for (int half = 0; half < 2; ++half) {
      bf16x8 a[2];
      #pragma unroll
      for (int mt = 0; mt < 2; ++mt)
        a[mt] = *(const bf16x8*)&wot[((size_t)s9 * 64 + wm * 32 + mt * 16 + l15) * 64 + half * 32 + lg * 8];
      #pragma unroll
      for (int nt = 0; nt < 8; ++nt) {
        int ty = wn * 8 + nt;
        bf16x8 b = *(const bf16x8*)&yp[((ty + dy) * 18 + l15 + dx) * 76 + half * 32 + lg * 8];
        #pragma unroll
        for (int mt = 0; mt < 2; ++mt)
          acc[mt][nt] = __builtin_amdgcn_mfma_f32_16x16x32_bf16(a[mt], b, acc[mt][nt], 0, 0, 0);
      }
    }
  }

  float* ob = out + (size_t)t * 64 * 65536;
  float bias[2][4];
  #pragma unroll
  for (int mt = 0; mt < 2; ++mt)
    #pragma unroll
    for (int r = 0; r < 4; ++r) bias[mt][r] = bo[wm * 32 + mt * 16 + lg * 4 + r];
  #pragma unroll
  for (int mt = 0; mt < 2; ++mt)
    #pragma unroll
    for (int nt = 0; nt < 8; ++nt) {
      int ty = wn * 8 + nt;
      #pragma unroll
      for (int r = 0; r < 4; ++r) {
        int co = wm * 32 + mt * 16 + lg * 4 + r;
        float res = b2f(*(const unsigned short*)&yp[((ty + 1) * 18 + l15 + 1) * 76 + co]);
        ob[(size_t)co * 65536 + (size_t)(y0 + ty) * 256 + x0 + l15] = res + acc[mt][nt][r] + bias[mt][r];
      }
    }
}

// ---------------- launcher ----------------
extern "C" void kernel_launch(void* const* d_in, const int* in_sizes, int n_in,
                              void* d_out, int out_size, void* d_ws, size_t ws_size,
                              hipStream_t stream) {
  const float* x  = (const float*)d_in[0];
  const float* Wq = (const float*)d_in[1];
  const float* bq = (const float*)d_in[2];
  const float* Wk = (const float*)d_in[3];
  const float* bk = (const float*)d_in[4];
  const float* Wv = (const float*)d_in[5];
  const float* bv = (const float*)d_in[6];
  const float* Wo = (const float*)d_in[7];
  const float* bo = (const float*)d_in[8];
  float* out = (float*)d_out;

  char* ws = (char*)d_ws;
  bf16* wt  = (bf16*)(ws + 0);
  bf16* wot = (bf16*)(ws + 110592);
  bf16* q   = (bf16*)(ws + 262144);              // reused as y_img after qk_gemm
  bf16* k   = (bf16*)(ws + 67371008);
  bf16* v   = (bf16*)(ws + 134479872);           // dead after transpose_v
  bf16* S   = (bf16*)(ws + 134479872);           // overlaps v (written after v dead)
  bf16* vt  = (bf16*)(ws + 268697600);
  bf16* y   = (bf16*)(ws + 262144);              // channels-last [8][256][256][64]
  // requires ws_size >= 335,806,464 bytes

  prep_w<<<216, 256, 0, stream>>>(Wq, Wk, Wv, Wo, wt, wot);
  qkv_conv<<<4096, 256, 0, stream>>>(x, wt, bq, bk, bv, q, k, v);
  transpose_v<<<8192, 256, 0, stream>>>(v, vt);
  qk_gemm<<<4096, 256, 0, stream>>>(q, k, S);
  softmax_rows<<<16384, 256, 0, stream>>>(S);
  pv_gemm<<<2048, 256, 0, stream>>>(S, vt, y);
  out_conv<<<2048, 256, 0, stream>>>(y, wot, bo, out);
}